// Round 1
// baseline (180.817 us; speedup 1.0000x reference)
//
#include <hip/hip_runtime.h>

// Sparse generative transposed-conv LSTM decoder (3 timesteps).
// Strategy: bucket output rows by kernel-offset k (8 buckets), then per-k
// blocks run gathered-row [128x128]@[128x256] (+ [128x64]@[64x64]) f16 MFMA
// GEMMs with weights held in registers, fused LSTM epilogue.

#define HID 64
#define KNUM 8
#define TM 128          // rows per tile
#define STEP_THREADS 512

typedef __attribute__((ext_vector_type(8))) _Float16 f16x8;
typedef __attribute__((ext_vector_type(4))) float f32x4;

__device__ __forceinline__ float fsig(float x) {
  return __builtin_amdgcn_rcpf(1.0f + __expf(-x));
}
__device__ __forceinline__ float ftanh_(float x) {
  float e = __expf(2.0f * x);
  return 1.0f - 2.0f * __builtin_amdgcn_rcpf(e + 1.0f);
}
__device__ __forceinline__ f16x8 to_h8(float4 a, float4 b) {
  f16x8 r;
  r[0] = (_Float16)a.x; r[1] = (_Float16)a.y; r[2] = (_Float16)a.z; r[3] = (_Float16)a.w;
  r[4] = (_Float16)b.x; r[5] = (_Float16)b.y; r[6] = (_Float16)b.z; r[7] = (_Float16)b.w;
  return r;
}

// ---- weight prep: transpose + f16-cast so B-fragments are contiguous ----
// WgT[k][co][ci], co in [0,256) over gates, ci in [0,128): ci<64 -> W_h, else W_i.
// WcT[k][co][ci], 64x64.
__global__ void prep_w_kernel(const float* __restrict__ Wi, const float* __restrict__ Wh,
                              const float* __restrict__ Wc,
                              _Float16* __restrict__ WgT, _Float16* __restrict__ WcT) {
  int stride = gridDim.x * blockDim.x;
  for (int idx = blockIdx.x * blockDim.x + threadIdx.x; idx < KNUM * 256 * 128; idx += stride) {
    int k  = idx >> 15;
    int co = (idx >> 7) & 255;
    int ci = idx & 127;
    float v = (ci < 64) ? Wh[(k * 64 + ci) * 256 + co]
                        : Wi[(k * 64 + ci - 64) * 256 + co];
    WgT[idx] = (_Float16)v;
  }
  for (int idx = blockIdx.x * blockDim.x + threadIdx.x; idx < KNUM * 64 * 64; idx += stride) {
    int k  = idx >> 12;
    int co = (idx >> 6) & 63;
    int ci = idx & 63;
    WcT[idx] = (_Float16)Wc[(k * 64 + ci) * 64 + co];
  }
}

// ---- bucketing by kofs ----
__global__ void zero_kernel(int* __restrict__ p) {
  if (threadIdx.x < KNUM) p[threadIdx.x] = 0;
}
__global__ void count_kernel(const int* __restrict__ kofs, int n, int* __restrict__ counts) {
  __shared__ int h[KNUM];
  if (threadIdx.x < KNUM) h[threadIdx.x] = 0;
  __syncthreads();
  for (int i = blockIdx.x * blockDim.x + threadIdx.x; i < n; i += gridDim.x * blockDim.x)
    atomicAdd(&h[kofs[i]], 1);
  __syncthreads();
  if (threadIdx.x < KNUM) atomicAdd(&counts[threadIdx.x], h[threadIdx.x]);
}
__global__ void scan_kernel(const int* __restrict__ counts, int* __restrict__ offsets,
                            int* __restrict__ cursor) {
  if (threadIdx.x == 0) {
    int s = 0;
    for (int k = 0; k < KNUM; ++k) { offsets[k] = s; cursor[k] = s; s += counts[k]; }
  }
}
__global__ void scatter_kernel(const int* __restrict__ kofs, int n,
                               int* __restrict__ cursor, int* __restrict__ order) {
  __shared__ int h[KNUM], base[KNUM];
  if (threadIdx.x < KNUM) h[threadIdx.x] = 0;
  __syncthreads();
  int chunk = (n + gridDim.x - 1) / gridDim.x;
  int c0 = blockIdx.x * chunk;
  int c1 = min(n, c0 + chunk);
  for (int i = c0 + threadIdx.x; i < c1; i += blockDim.x)
    atomicAdd(&h[kofs[i]], 1);
  __syncthreads();
  if (threadIdx.x < KNUM) {
    base[threadIdx.x] = atomicAdd(&cursor[threadIdx.x], h[threadIdx.x]);
    h[threadIdx.x] = 0;
  }
  __syncthreads();
  for (int i = c0 + threadIdx.x; i < c1; i += blockDim.x) {
    int k = kofs[i];
    int pos = atomicAdd(&h[k], 1);
    order[base[k] + pos] = i;   // bucket order is nondeterministic but output is row-indexed -> deterministic
  }
}

// ---- fused step kernel ----
// grid = 8 * bpk blocks; block b handles bucket kb = b&7.
// 8 waves: wr = wave>>2 (row half), wc = wave&3 (16-channel slice).
// Each wave computes, for its rows x channels, all four gate columns
// {ch, ch+64, ch+128, ch+192} plus c_up column ch -> epilogue is register-local.
template <bool FIRST, bool LAST>
__global__ __launch_bounds__(STEP_THREADS, 2)
void lstm_step_kernel(const float* __restrict__ x, const float* __restrict__ h_in,
                      const float* __restrict__ c_in, const int* __restrict__ parent,
                      const int* __restrict__ order, const int* __restrict__ counts,
                      const int* __restrict__ offsets, const _Float16* __restrict__ WgT,
                      const _Float16* __restrict__ WcT, float* __restrict__ h_out,
                      float* __restrict__ c_out, int bpk) {
  __shared__ __align__(16) _Float16 A[TM][136];   // [h(0:64)|x(64:128)] + pad
  __shared__ __align__(16) _Float16 Cg[TM][72];   // c_in gathered + pad
  __shared__ int jidx[TM];

  const int kb = blockIdx.x & 7;
  const int bi = blockIdx.x >> 3;
  const int cnt = counts[kb];
  const int off = offsets[kb];
  const int ntiles = (cnt + TM - 1) / TM;

  const int lane = threadIdx.x & 63;
  const int wid  = threadIdx.x >> 6;
  const int wr   = wid >> 2;
  const int wc   = wid & 3;
  const int l15  = lane & 15;
  const int kg   = lane >> 4;

  // preload B fragments (weights) into registers, once per block
  f16x8 bg[4][4];   // [gate][kstep]
  f16x8 bc[2];
  {
    const _Float16* wgp = WgT + (size_t)kb * (256 * 128);
#pragma unroll
    for (int g = 0; g < 4; ++g)
#pragma unroll
      for (int ks = 0; ks < 4; ++ks)
        bg[g][ks] = *(const f16x8*)(wgp + (size_t)(64 * g + 16 * wc + l15) * 128 + ks * 32 + kg * 8);
    if constexpr (!FIRST) {
      const _Float16* wcp = WcT + (size_t)kb * (64 * 64);
#pragma unroll
      for (int ks = 0; ks < 2; ++ks)
        bc[ks] = *(const f16x8*)(wcp + (size_t)(16 * wc + l15) * 64 + ks * 32 + kg * 8);
    } else {
      bc[0] = f16x8{};
      bc[1] = f16x8{};
    }
  }

  const int gr = threadIdx.x >> 2;  // gather row 0..127
  const int gq = threadIdx.x & 3;   // 16-channel quarter

  for (int t = bi; t < ntiles; t += bpk) {
    __syncthreads();  // previous tile's LDS readers done
    // ---- gather rows -> LDS (f32 -> f16) ----
    {
      int grow = t * TM + gr;
      if (grow < cnt) {
        int j = order[off + grow];
        if (gq == 0) jidx[gr] = j;
        int p = parent[j];
        const float4* xb = (const float4*)(x + (size_t)p * 64 + gq * 16);
        float4 v0 = xb[0], v1 = xb[1], v2 = xb[2], v3 = xb[3];
        *(f16x8*)&A[gr][64 + gq * 16]     = to_h8(v0, v1);
        *(f16x8*)&A[gr][64 + gq * 16 + 8] = to_h8(v2, v3);
        if constexpr (!FIRST) {
          const float4* hb = (const float4*)(h_in + (size_t)p * 64 + gq * 16);
          float4 h0 = hb[0], h1 = hb[1], h2 = hb[2], h3 = hb[3];
          *(f16x8*)&A[gr][gq * 16]     = to_h8(h0, h1);
          *(f16x8*)&A[gr][gq * 16 + 8] = to_h8(h2, h3);
          const float4* cb = (const float4*)(c_in + (size_t)p * 64 + gq * 16);
          float4 c0 = cb[0], c1 = cb[1], c2 = cb[2], c3 = cb[3];
          *(f16x8*)&Cg[gr][gq * 16]     = to_h8(c0, c1);
          *(f16x8*)&Cg[gr][gq * 16 + 8] = to_h8(c2, c3);
        }
      } else {
        if (gq == 0) jidx[gr] = -1;
        f16x8 z = {};
        *(f16x8*)&A[gr][64 + gq * 16]     = z;
        *(f16x8*)&A[gr][64 + gq * 16 + 8] = z;
        if constexpr (!FIRST) {
          *(f16x8*)&A[gr][gq * 16]      = z;
          *(f16x8*)&A[gr][gq * 16 + 8]  = z;
          *(f16x8*)&Cg[gr][gq * 16]     = z;
          *(f16x8*)&Cg[gr][gq * 16 + 8] = z;
        }
      }
    }
    __syncthreads();

    // ---- MFMA: gates [128x256], c_up [128x64] ----
    f32x4 aG[4][4];
    f32x4 aC[4];
#pragma unroll
    for (int rf = 0; rf < 4; ++rf) {
#pragma unroll
      for (int g = 0; g < 4; ++g) aG[rf][g] = f32x4{0.f, 0.f, 0.f, 0.f};
      aC[rf] = f32x4{0.f, 0.f, 0.f, 0.f};
    }
#pragma unroll
    for (int ks = (FIRST ? 2 : 0); ks < 4; ++ks) {
#pragma unroll
      for (int rf = 0; rf < 4; ++rf) {
        f16x8 a = *(const f16x8*)&A[64 * wr + 16 * rf + l15][ks * 32 + kg * 8];
        aG[rf][0] = __builtin_amdgcn_mfma_f32_16x16x32_f16(a, bg[0][ks], aG[rf][0], 0, 0, 0);
        aG[rf][1] = __builtin_amdgcn_mfma_f32_16x16x32_f16(a, bg[1][ks], aG[rf][1], 0, 0, 0);
        aG[rf][2] = __builtin_amdgcn_mfma_f32_16x16x32_f16(a, bg[2][ks], aG[rf][2], 0, 0, 0);
        aG[rf][3] = __builtin_amdgcn_mfma_f32_16x16x32_f16(a, bg[3][ks], aG[rf][3], 0, 0, 0);
      }
    }
    if constexpr (!FIRST) {
#pragma unroll
      for (int ks = 0; ks < 2; ++ks) {
#pragma unroll
        for (int rf = 0; rf < 4; ++rf) {
          f16x8 a = *(const f16x8*)&Cg[64 * wr + 16 * rf + l15][ks * 32 + kg * 8];
          aC[rf] = __builtin_amdgcn_mfma_f32_16x16x32_f16(a, bc[ks], aC[rf], 0, 0, 0);
        }
      }
    }

    // ---- LSTM epilogue (register-local) + scatter store ----
#pragma unroll
    for (int rf = 0; rf < 4; ++rf) {
#pragma unroll
      for (int r = 0; r < 4; ++r) {
        int row = 64 * wr + 16 * rf + kg * 4 + r;  // C/D layout: row=(lane>>4)*4+reg, col=lane&15
        int j = jidx[row];
        if (j < 0) continue;
        float ing = fsig(aG[rf][0][r]);
        float fg  = fsig(aG[rf][1][r]);
        float cgt = fsig(aG[rf][2][r]);   // reference uses sigmoid for cell gate
        float og  = fsig(aG[rf][3][r]);
        float cup = FIRST ? 0.0f : aC[rf][r];
        float cxv = fg * cup + ing * cgt;
        float hxv = og * ftanh_(cxv);
        size_t o = (size_t)j * 64 + (16 * wc + l15);
        h_out[o] = hxv;
        if constexpr (!LAST) c_out[o] = cxv;
      }
    }
  }
}

static inline int idiv_up(int a, int b) { return (a + b - 1) / b; }

template <bool FIRST, bool LAST>
static void run_step(const float* x, const float* h_in, const float* c_in,
                     const int* parent, const int* kofs, int nout,
                     int* counts, int* offsets, int* cursor, int* order,
                     const _Float16* WgT, const _Float16* WcT,
                     float* h_out, float* c_out, hipStream_t stream) {
  zero_kernel<<<1, 64, 0, stream>>>(counts);
  count_kernel<<<256, 256, 0, stream>>>(kofs, nout, counts);
  scan_kernel<<<1, 64, 0, stream>>>(counts, offsets, cursor);
  scatter_kernel<<<256, 256, 0, stream>>>(kofs, nout, cursor, order);
  int bpk = idiv_up(nout, 8 * TM);
  if (bpk > 64) bpk = 64;
  if (bpk < 1) bpk = 1;
  lstm_step_kernel<FIRST, LAST><<<dim3(8 * bpk), dim3(STEP_THREADS), 0, stream>>>(
      x, h_in, c_in, parent, order, counts, offsets, WgT, WcT, h_out, c_out, bpk);
}

extern "C" void kernel_launch(void* const* d_in, const int* in_sizes, int n_in,
                              void* d_out, int out_size, void* d_ws, size_t ws_size,
                              hipStream_t stream) {
  const float* x0 = (const float*)d_in[0];
  const float* x1 = (const float*)d_in[1];
  const float* x2 = (const float*)d_in[2];
  const float* Wi = (const float*)d_in[3];
  const float* Wh = (const float*)d_in[4];
  const float* Wc = (const float*)d_in[5];
  const int* parent0 = (const int*)d_in[6];
  const int* kofs0   = (const int*)d_in[7];
  const int* parent1 = (const int*)d_in[8];
  const int* kofs1   = (const int*)d_in[9];
  const int* parent2 = (const int*)d_in[10];
  const int* kofs2   = (const int*)d_in[11];
  const int N1 = in_sizes[6];
  const int N2 = in_sizes[8];
  const int N3 = in_sizes[10];

  // workspace carve (all 256B-aligned); total ~53 MB
  char* w = (char*)d_ws;
  auto carve = [&](size_t bytes) {
    char* p = w;
    w += (bytes + 255) & ~(size_t)255;
    return p;
  };
  _Float16* WgT = (_Float16*)carve((size_t)KNUM * 256 * 128 * 2);
  _Float16* WcT = (_Float16*)carve((size_t)KNUM * 64 * 64 * 2);
  int* counts   = (int*)carve(KNUM * sizeof(int));
  int* offsets  = (int*)carve(KNUM * sizeof(int));
  int* cursor   = (int*)carve(KNUM * sizeof(int));
  int* order    = (int*)carve((size_t)N3 * sizeof(int));
  float* h_a    = (float*)carve((size_t)N1 * 64 * sizeof(float));
  float* c_a    = (float*)carve((size_t)N1 * 64 * sizeof(float));
  float* h_b    = (float*)carve((size_t)N2 * 64 * sizeof(float));
  float* c_b    = (float*)carve((size_t)N2 * 64 * sizeof(float));
  (void)ws_size; (void)n_in; (void)out_size;

  prep_w_kernel<<<64, 256, 0, stream>>>(Wi, Wh, Wc, WgT, WcT);

  // t=0: h/c states are zero -> FIRST specialization (no h/c gather, no W_c)
  run_step<true, false>(x0, nullptr, nullptr, parent0, kofs0, N1,
                        counts, offsets, cursor, order, WgT, WcT, h_a, c_a, stream);
  run_step<false, false>(x1, h_a, c_a, parent1, kofs1, N2,
                         counts, offsets, cursor, order, WgT, WcT, h_b, c_b, stream);
  run_step<false, true>(x2, h_b, c_b, parent2, kofs2, N3,
                        counts, offsets, cursor, order, WgT, WcT, (float*)d_out, nullptr, stream);
}

// Round 2
// 147.360 us; speedup vs baseline: 1.2270x; 1.2270x over previous
//
#include <hip/hip_runtime.h>

// Sparse generative transposed-conv LSTM decoder (3 timesteps).
// R2: software-pipelined step kernel (T14 async-stage: issue next tile's
// gathers before epilogue, convert+LDS-write after the barrier), porder[]
// to break the order->parent dependent chain, fused bucketing (7 launches).

#define HID 64
#define KNUM 8
#define TM 64           // rows per tile
#define STEP_THREADS 512

typedef __attribute__((ext_vector_type(8))) _Float16 f16x8;
typedef __attribute__((ext_vector_type(4))) float f32x4;

__device__ __forceinline__ float fsig(float x) {
  return __builtin_amdgcn_rcpf(1.0f + __expf(-x));
}
__device__ __forceinline__ float ftanh_(float x) {
  float e = __expf(2.0f * x);
  return 1.0f - 2.0f * __builtin_amdgcn_rcpf(e + 1.0f);
}
__device__ __forceinline__ f16x8 to_h8(float4 a, float4 b) {
  f16x8 r;
  r[0] = (_Float16)a.x; r[1] = (_Float16)a.y; r[2] = (_Float16)a.z; r[3] = (_Float16)a.w;
  r[4] = (_Float16)b.x; r[5] = (_Float16)b.y; r[6] = (_Float16)b.z; r[7] = (_Float16)b.w;
  return r;
}

// ---- weight prep (+ zero the 3x8 count array) ----
// WgT[k][co][ci], co in [0,256) over gates, ci in [0,128): ci<64 -> W_h, else W_i.
__global__ void prep_w_kernel(const float* __restrict__ Wi, const float* __restrict__ Wh,
                              const float* __restrict__ Wc,
                              _Float16* __restrict__ WgT, _Float16* __restrict__ WcT,
                              int* __restrict__ counts) {
  if (blockIdx.x == 0 && threadIdx.x < 3 * KNUM) counts[threadIdx.x] = 0;
  int stride = gridDim.x * blockDim.x;
  for (int idx = blockIdx.x * blockDim.x + threadIdx.x; idx < KNUM * 256 * 128; idx += stride) {
    int k  = idx >> 15;
    int co = (idx >> 7) & 255;
    int ci = idx & 127;
    float v = (ci < 64) ? Wh[(k * 64 + ci) * 256 + co]
                        : Wi[(k * 64 + ci - 64) * 256 + co];
    WgT[idx] = (_Float16)v;
  }
  for (int idx = blockIdx.x * blockDim.x + threadIdx.x; idx < KNUM * 64 * 64; idx += stride) {
    int k  = idx >> 12;
    int co = (idx >> 6) & 63;
    int ci = idx & 63;
    WcT[idx] = (_Float16)Wc[(k * 64 + ci) * 64 + co];
  }
}

// ---- fused bucketing for all 3 steps ----
// grid=512 blocks: [0,32)->step0, [32,160)->step1, [160,512)->step2
__device__ __forceinline__ void seg_select(int b, int& seg, int& rb, int& nb) {
  if (b < 32)       { seg = 0; rb = b;       nb = 32;  }
  else if (b < 160) { seg = 1; rb = b - 32;  nb = 128; }
  else              { seg = 2; rb = b - 160; nb = 352; }
}

__global__ void count_all_kernel(const int* __restrict__ k0, int n0,
                                 const int* __restrict__ k1, int n1,
                                 const int* __restrict__ k2, int n2,
                                 int* __restrict__ counts) {
  int seg, rb, nb;
  seg_select(blockIdx.x, seg, rb, nb);
  const int* kp = seg == 0 ? k0 : seg == 1 ? k1 : k2;
  int n = seg == 0 ? n0 : seg == 1 ? n1 : n2;
  int* cbase = counts + seg * KNUM;
  __shared__ int h[KNUM];
  if (threadIdx.x < KNUM) h[threadIdx.x] = 0;
  __syncthreads();
  for (int i = rb * blockDim.x + threadIdx.x; i < n; i += nb * blockDim.x)
    atomicAdd(&h[kp[i]], 1);
  __syncthreads();
  if (threadIdx.x < KNUM) atomicAdd(&cbase[threadIdx.x], h[threadIdx.x]);
}

__global__ void scan_all_kernel(const int* __restrict__ counts, int* __restrict__ offsets,
                                int* __restrict__ cursor) {
  if (threadIdx.x == 0) {
#pragma unroll
    for (int s = 0; s < 3; ++s) {
      int acc = 0;
      for (int k = 0; k < KNUM; ++k) {
        offsets[s * KNUM + k] = acc;
        cursor[s * KNUM + k] = acc;
        acc += counts[s * KNUM + k];
      }
    }
  }
}

__global__ void scatter_all_kernel(const int* __restrict__ k0, const int* __restrict__ p0, int n0,
                                   int* __restrict__ o0, int* __restrict__ q0,
                                   const int* __restrict__ k1, const int* __restrict__ p1, int n1,
                                   int* __restrict__ o1, int* __restrict__ q1,
                                   const int* __restrict__ k2, const int* __restrict__ p2, int n2,
                                   int* __restrict__ o2, int* __restrict__ q2,
                                   int* __restrict__ cursor) {
  int seg, rb, nb;
  seg_select(blockIdx.x, seg, rb, nb);
  const int* kp = seg == 0 ? k0 : seg == 1 ? k1 : k2;
  const int* pp = seg == 0 ? p0 : seg == 1 ? p1 : p2;
  int n = seg == 0 ? n0 : seg == 1 ? n1 : n2;
  int* order  = seg == 0 ? o0 : seg == 1 ? o1 : o2;
  int* porder = seg == 0 ? q0 : seg == 1 ? q1 : q2;
  int* cur = cursor + seg * KNUM;

  __shared__ int h[KNUM], base[KNUM];
  if (threadIdx.x < KNUM) h[threadIdx.x] = 0;
  __syncthreads();
  int chunk = (n + nb - 1) / nb;
  int c0 = rb * chunk;
  int c1 = min(n, c0 + chunk);
  for (int i = c0 + threadIdx.x; i < c1; i += blockDim.x)
    atomicAdd(&h[kp[i]], 1);
  __syncthreads();
  if (threadIdx.x < KNUM) {
    base[threadIdx.x] = atomicAdd(&cur[threadIdx.x], h[threadIdx.x]);
    h[threadIdx.x] = 0;
  }
  __syncthreads();
  for (int i = c0 + threadIdx.x; i < c1; i += blockDim.x) {
    int k = kp[i];
    int pos = base[k] + atomicAdd(&h[k], 1);
    order[pos] = i;          // bucket order nondeterministic; output row-indexed -> deterministic
    porder[pos] = pp[i];
  }
}

// ---- fused pipelined step kernel ----
// grid = 8*bpk blocks; block handles bucket kb = blockIdx.x&7, tiles bi, bi+bpk, ...
// 8 waves: wr = wid>>2 (32-row half), wc = wid&3 (16-channel slice).
// Pipeline per tile: [convert staged regs -> LDS] sync [issue idx t+1] [MFMA]
// [issue row gathers t+1] [epilogue].
template <bool FIRST, bool LAST>
__global__ __launch_bounds__(STEP_THREADS)
void lstm_step_kernel(const float* __restrict__ x, const float* __restrict__ h_in,
                      const float* __restrict__ c_in,
                      const int* __restrict__ order, const int* __restrict__ porder,
                      const int* __restrict__ counts, const int* __restrict__ offsets,
                      const _Float16* __restrict__ WgT, const _Float16* __restrict__ WcT,
                      float* __restrict__ h_out, float* __restrict__ c_out, int bpk) {
  __shared__ __align__(16) _Float16 A[TM][136];   // [h(0:64)|x(64:128)] + pad
  __shared__ __align__(16) _Float16 Cg[TM][72];   // c_in gathered + pad
  __shared__ int jidx[TM];

  const int kb = blockIdx.x & 7;
  const int bi = blockIdx.x >> 3;
  const int cnt = counts[kb];
  const int off = offsets[kb];
  const int ntiles = (cnt + TM - 1) / TM;
  if (bi >= ntiles) return;

  const int lane = threadIdx.x & 63;
  const int wid  = threadIdx.x >> 6;
  const int wr   = wid >> 2;
  const int wc   = wid & 3;
  const int l15  = lane & 15;
  const int kg   = lane >> 4;

  // B fragments in registers, loaded once per block
  f16x8 bg[4][4];   // [gate][kstep]
  f16x8 bc[2];
  {
    const _Float16* wgp = WgT + (size_t)kb * (256 * 128);
#pragma unroll
    for (int g = 0; g < 4; ++g)
#pragma unroll
      for (int ks = 0; ks < 4; ++ks)
        bg[g][ks] = *(const f16x8*)(wgp + (size_t)(64 * g + 16 * wc + l15) * 128 + ks * 32 + kg * 8);
    if constexpr (!FIRST) {
      const _Float16* wcp = WcT + (size_t)kb * (64 * 64);
#pragma unroll
      for (int ks = 0; ks < 2; ++ks)
        bc[ks] = *(const f16x8*)(wcp + (size_t)(16 * wc + l15) * 64 + ks * 32 + kg * 8);
    } else {
      bc[0] = f16x8{}; bc[1] = f16x8{};
    }
  }

  const int gr  = threadIdx.x >> 3;  // gather row 0..63
  const int gq8 = threadIdx.x & 7;   // 8-channel slice

  // staged (next-tile) registers
  int sj = -1, sp = 0;
  bool sv = false;
  float4 sx0{}, sx1{}, sh0{}, sh1{}, sc0{}, sc1{};

  auto issue_idx = [&](int tt, int& j_, int& p_, bool& v_) {
    int grow = tt * TM + gr;
    v_ = (tt < ntiles) && (grow < cnt);
    j_ = -1; p_ = 0;
    if (v_) {
      if (gq8 == 0) j_ = order[off + grow];
      p_ = porder[off + grow];
    }
  };
  auto issue_rows = [&](int p_, bool v_) {
    if (v_) {
      const float4* xb = (const float4*)(x + (size_t)p_ * 64 + gq8 * 8);
      sx0 = xb[0]; sx1 = xb[1];
      if constexpr (!FIRST) {
        const float4* hb = (const float4*)(h_in + (size_t)p_ * 64 + gq8 * 8);
        sh0 = hb[0]; sh1 = hb[1];
        const float4* cb = (const float4*)(c_in + (size_t)p_ * 64 + gq8 * 8);
        sc0 = cb[0]; sc1 = cb[1];
      }
    } else {
      sx0 = float4{}; sx1 = float4{};
      if constexpr (!FIRST) { sh0 = float4{}; sh1 = float4{}; sc0 = float4{}; sc1 = float4{}; }
    }
  };

  // prologue: stage tile bi
  issue_idx(bi, sj, sp, sv);
  issue_rows(sp, sv);

  for (int t = bi; t < ntiles; t += bpk) {
    __syncthreads();  // previous tile's LDS readers done
    // drain staged regs -> LDS (f32->f16)
    if (gq8 == 0) jidx[gr] = sj;
    *(f16x8*)&A[gr][64 + gq8 * 8] = to_h8(sx0, sx1);
    if constexpr (!FIRST) {
      *(f16x8*)&A[gr][gq8 * 8]  = to_h8(sh0, sh1);
      *(f16x8*)&Cg[gr][gq8 * 8] = to_h8(sc0, sc1);
    }
    __syncthreads();

    // issue next tile's index loads (fly during MFMA)
    int nj, np; bool nv;
    issue_idx(t + bpk, nj, np, nv);

    // MFMA: gates [64x256], c_up [64x64]
    f32x4 aG[2][4];
    f32x4 aC[2];
#pragma unroll
    for (int rf = 0; rf < 2; ++rf) {
#pragma unroll
      for (int g = 0; g < 4; ++g) aG[rf][g] = f32x4{0.f, 0.f, 0.f, 0.f};
      aC[rf] = f32x4{0.f, 0.f, 0.f, 0.f};
    }
#pragma unroll
    for (int ks = (FIRST ? 2 : 0); ks < 4; ++ks) {
#pragma unroll
      for (int rf = 0; rf < 2; ++rf) {
        f16x8 a = *(const f16x8*)&A[32 * wr + 16 * rf + l15][ks * 32 + kg * 8];
        aG[rf][0] = __builtin_amdgcn_mfma_f32_16x16x32_f16(a, bg[0][ks], aG[rf][0], 0, 0, 0);
        aG[rf][1] = __builtin_amdgcn_mfma_f32_16x16x32_f16(a, bg[1][ks], aG[rf][1], 0, 0, 0);
        aG[rf][2] = __builtin_amdgcn_mfma_f32_16x16x32_f16(a, bg[2][ks], aG[rf][2], 0, 0, 0);
        aG[rf][3] = __builtin_amdgcn_mfma_f32_16x16x32_f16(a, bg[3][ks], aG[rf][3], 0, 0, 0);
      }
    }
    if constexpr (!FIRST) {
#pragma unroll
      for (int ks = 0; ks < 2; ++ks) {
#pragma unroll
        for (int rf = 0; rf < 2; ++rf) {
          f16x8 a = *(const f16x8*)&Cg[32 * wr + 16 * rf + l15][ks * 32 + kg * 8];
          aC[rf] = __builtin_amdgcn_mfma_f32_16x16x32_f16(a, bc[ks], aC[rf], 0, 0, 0);
        }
      }
    }

    // issue next tile's row gathers into float4 regs (waits only on idx loads;
    // latency hides under the epilogue below + other waves' MFMA)
    issue_rows(np, nv);
    sj = nj; sp = np; sv = nv;

    // LSTM epilogue + scatter store
#pragma unroll
    for (int rf = 0; rf < 2; ++rf) {
#pragma unroll
      for (int r = 0; r < 4; ++r) {
        int row = 32 * wr + 16 * rf + kg * 4 + r;  // C/D: row=(lane>>4)*4+reg, col=lane&15
        int j = jidx[row];
        if (j < 0) continue;
        float ing = fsig(aG[rf][0][r]);
        float fg  = fsig(aG[rf][1][r]);
        float cgt = fsig(aG[rf][2][r]);   // reference uses sigmoid for cell gate
        float og  = fsig(aG[rf][3][r]);
        float cup = FIRST ? 0.0f : aC[rf][r];
        float cxv = fg * cup + ing * cgt;
        float hxv = og * ftanh_(cxv);
        size_t o = (size_t)j * 64 + (16 * wc + l15);
        h_out[o] = hxv;
        if constexpr (!LAST) c_out[o] = cxv;
      }
    }
  }
}

static inline int idiv_up(int a, int b) { return (a + b - 1) / b; }

template <bool FIRST, bool LAST>
static void run_step(const float* x, const float* h_in, const float* c_in,
                     const int* order, const int* porder, int nout,
                     const int* counts, const int* offsets,
                     const _Float16* WgT, const _Float16* WcT,
                     float* h_out, float* c_out, hipStream_t stream) {
  int bpk = idiv_up(nout, 8 * TM);
  if (bpk > 128) bpk = 128;
  if (bpk < 1) bpk = 1;
  lstm_step_kernel<FIRST, LAST><<<dim3(8 * bpk), dim3(STEP_THREADS), 0, stream>>>(
      x, h_in, c_in, order, porder, counts, offsets, WgT, WcT, h_out, c_out, bpk);
}

extern "C" void kernel_launch(void* const* d_in, const int* in_sizes, int n_in,
                              void* d_out, int out_size, void* d_ws, size_t ws_size,
                              hipStream_t stream) {
  const float* x0 = (const float*)d_in[0];
  const float* x1 = (const float*)d_in[1];
  const float* x2 = (const float*)d_in[2];
  const float* Wi = (const float*)d_in[3];
  const float* Wh = (const float*)d_in[4];
  const float* Wc = (const float*)d_in[5];
  const int* parent0 = (const int*)d_in[6];
  const int* kofs0   = (const int*)d_in[7];
  const int* parent1 = (const int*)d_in[8];
  const int* kofs1   = (const int*)d_in[9];
  const int* parent2 = (const int*)d_in[10];
  const int* kofs2   = (const int*)d_in[11];
  const int N1 = in_sizes[6];
  const int N2 = in_sizes[8];
  const int N3 = in_sizes[10];

  char* w = (char*)d_ws;
  auto carve = [&](size_t bytes) {
    char* p = w;
    w += (bytes + 255) & ~(size_t)255;
    return p;
  };
  _Float16* WgT = (_Float16*)carve((size_t)KNUM * 256 * 128 * 2);
  _Float16* WcT = (_Float16*)carve((size_t)KNUM * 64 * 64 * 2);
  int* counts   = (int*)carve(3 * KNUM * sizeof(int));
  int* offsets  = (int*)carve(3 * KNUM * sizeof(int));
  int* cursor   = (int*)carve(3 * KNUM * sizeof(int));
  int* ord0     = (int*)carve((size_t)N1 * sizeof(int));
  int* por0     = (int*)carve((size_t)N1 * sizeof(int));
  int* ord1     = (int*)carve((size_t)N2 * sizeof(int));
  int* por1     = (int*)carve((size_t)N2 * sizeof(int));
  int* ord2     = (int*)carve((size_t)N3 * sizeof(int));
  int* por2     = (int*)carve((size_t)N3 * sizeof(int));
  float* h_a    = (float*)carve((size_t)N1 * 64 * sizeof(float));
  float* c_a    = (float*)carve((size_t)N1 * 64 * sizeof(float));
  float* h_b    = (float*)carve((size_t)N2 * 64 * sizeof(float));
  float* c_b    = (float*)carve((size_t)N2 * 64 * sizeof(float));
  (void)ws_size; (void)n_in; (void)out_size;

  prep_w_kernel<<<64, 256, 0, stream>>>(Wi, Wh, Wc, WgT, WcT, counts);
  count_all_kernel<<<512, 256, 0, stream>>>(kofs0, N1, kofs1, N2, kofs2, N3, counts);
  scan_all_kernel<<<1, 64, 0, stream>>>(counts, offsets, cursor);
  scatter_all_kernel<<<512, 256, 0, stream>>>(kofs0, parent0, N1, ord0, por0,
                                              kofs1, parent1, N2, ord1, por1,
                                              kofs2, parent2, N3, ord2, por2, cursor);

  run_step<true, false>(x0, nullptr, nullptr, ord0, por0, N1,
                        counts + 0 * KNUM, offsets + 0 * KNUM, WgT, WcT, h_a, c_a, stream);
  run_step<false, false>(x1, h_a, c_a, ord1, por1, N2,
                         counts + 1 * KNUM, offsets + 1 * KNUM, WgT, WcT, h_b, c_b, stream);
  run_step<false, true>(x2, h_b, c_b, ord2, por2, N3,
                        counts + 2 * KNUM, offsets + 2 * KNUM, WgT, WcT, (float*)d_out, nullptr, stream);
}

// Round 3
// 118.681 us; speedup vs baseline: 1.5236x; 1.2416x over previous
//
#include <hip/hip_runtime.h>

// Sparse generative transposed-conv LSTM decoder (3 timesteps).
// R3: all-f16 data path (pre-converted x, f16 h/c intermediates), 256-thread
// blocks (4 independent barrier domains/CU), gathers issued before MFMA with
// 2-tile-ahead index prefetch, 6 total dispatches.

#define KNUM 8
#define TM 32           // rows per tile
#define STEP_THREADS 256

typedef __attribute__((ext_vector_type(8))) _Float16 f16x8;
typedef __attribute__((ext_vector_type(4))) float f32x4;

__device__ __forceinline__ float fsig(float x) {
  return __builtin_amdgcn_rcpf(1.0f + __expf(-x));
}
__device__ __forceinline__ float ftanh_(float x) {
  float e = __expf(2.0f * x);
  return 1.0f - 2.0f * __builtin_amdgcn_rcpf(e + 1.0f);
}
__device__ __forceinline__ f16x8 to_h8(float4 a, float4 b) {
  f16x8 r;
  r[0] = (_Float16)a.x; r[1] = (_Float16)a.y; r[2] = (_Float16)a.z; r[3] = (_Float16)a.w;
  r[4] = (_Float16)b.x; r[5] = (_Float16)b.y; r[6] = (_Float16)b.z; r[7] = (_Float16)b.w;
  return r;
}

// ---- prep: zero counters, transpose+cast weights, cast x inputs to f16 ----
__global__ void prep_kernel(const float* __restrict__ Wi, const float* __restrict__ Wh,
                            const float* __restrict__ Wc,
                            const float* __restrict__ x0, const float* __restrict__ x1,
                            const float* __restrict__ x2, int ne0, int ne1, int ne2,
                            _Float16* __restrict__ WgT, _Float16* __restrict__ WcT,
                            _Float16* __restrict__ x0f, _Float16* __restrict__ x1f,
                            _Float16* __restrict__ x2f,
                            int* __restrict__ counts, int* __restrict__ cursor) {
  int tid = blockIdx.x * blockDim.x + threadIdx.x;
  int stride = gridDim.x * blockDim.x;
  if (tid < 3 * KNUM) { counts[tid] = 0; cursor[tid] = 0; }
  // WgT[k][co][ci]: ci<64 -> W_h, else W_i (transposed, f16)
  for (int idx = tid; idx < KNUM * 256 * 128; idx += stride) {
    int k  = idx >> 15;
    int co = (idx >> 7) & 255;
    int ci = idx & 127;
    float v = (ci < 64) ? Wh[(k * 64 + ci) * 256 + co]
                        : Wi[(k * 64 + ci - 64) * 256 + co];
    WgT[idx] = (_Float16)v;
  }
  for (int idx = tid; idx < KNUM * 64 * 64; idx += stride) {
    int k  = idx >> 12;
    int co = (idx >> 6) & 63;
    int ci = idx & 63;
    WcT[idx] = (_Float16)Wc[(k * 64 + ci) * 64 + co];
  }
  for (int i = tid; i < (ne0 >> 3); i += stride) {
    float4 a = ((const float4*)x0)[2 * i], b = ((const float4*)x0)[2 * i + 1];
    ((f16x8*)x0f)[i] = to_h8(a, b);
  }
  for (int i = tid; i < (ne1 >> 3); i += stride) {
    float4 a = ((const float4*)x1)[2 * i], b = ((const float4*)x1)[2 * i + 1];
    ((f16x8*)x1f)[i] = to_h8(a, b);
  }
  for (int i = tid; i < (ne2 >> 3); i += stride) {
    float4 a = ((const float4*)x2)[2 * i], b = ((const float4*)x2)[2 * i + 1];
    ((f16x8*)x2f)[i] = to_h8(a, b);
  }
}

// ---- bucketing ----
__device__ __forceinline__ void seg_select(int b, int& seg, int& rb, int& nb) {
  if (b < 32)       { seg = 0; rb = b;       nb = 32;  }
  else if (b < 160) { seg = 1; rb = b - 32;  nb = 128; }
  else              { seg = 2; rb = b - 160; nb = 352; }
}

__global__ void count_all_kernel(const int* __restrict__ k0, int n0,
                                 const int* __restrict__ k1, int n1,
                                 const int* __restrict__ k2, int n2,
                                 int* __restrict__ counts) {
  int seg, rb, nb;
  seg_select(blockIdx.x, seg, rb, nb);
  const int* kp = seg == 0 ? k0 : seg == 1 ? k1 : k2;
  int n = seg == 0 ? n0 : seg == 1 ? n1 : n2;
  int* cbase = counts + seg * KNUM;
  __shared__ int h[KNUM];
  if (threadIdx.x < KNUM) h[threadIdx.x] = 0;
  __syncthreads();
  for (int i = rb * blockDim.x + threadIdx.x; i < n; i += nb * blockDim.x)
    atomicAdd(&h[kp[i]], 1);
  __syncthreads();
  if (threadIdx.x < KNUM) atomicAdd(&cbase[threadIdx.x], h[threadIdx.x]);
}

// scatter with in-block scan (offsets derived from counts; cursor pre-zeroed)
__global__ void scatter_all_kernel(const int* __restrict__ k0, const int* __restrict__ p0, int n0,
                                   int* __restrict__ o0, int* __restrict__ q0,
                                   const int* __restrict__ k1, const int* __restrict__ p1, int n1,
                                   int* __restrict__ o1, int* __restrict__ q1,
                                   const int* __restrict__ k2, const int* __restrict__ p2, int n2,
                                   int* __restrict__ o2, int* __restrict__ q2,
                                   const int* __restrict__ counts, int* __restrict__ cursor) {
  int seg, rb, nb;
  seg_select(blockIdx.x, seg, rb, nb);
  const int* kp = seg == 0 ? k0 : seg == 1 ? k1 : k2;
  const int* pp = seg == 0 ? p0 : seg == 1 ? p1 : p2;
  int n = seg == 0 ? n0 : seg == 1 ? n1 : n2;
  int* order  = seg == 0 ? o0 : seg == 1 ? o1 : o2;
  int* porder = seg == 0 ? q0 : seg == 1 ? q1 : q2;

  __shared__ int h[KNUM], base[KNUM];
  if (threadIdx.x < KNUM) h[threadIdx.x] = 0;
  __syncthreads();
  int chunk = (n + nb - 1) / nb;
  int c0 = rb * chunk;
  int c1 = min(n, c0 + chunk);
  for (int i = c0 + threadIdx.x; i < c1; i += blockDim.x)
    atomicAdd(&h[kp[i]], 1);
  __syncthreads();
  if (threadIdx.x < KNUM) {
    int offk = 0;
    for (int k = 0; k < (int)threadIdx.x; ++k) offk += counts[seg * KNUM + k];
    base[threadIdx.x] = offk + atomicAdd(&cursor[seg * KNUM + threadIdx.x], h[threadIdx.x]);
    h[threadIdx.x] = 0;
  }
  __syncthreads();
  for (int i = c0 + threadIdx.x; i < c1; i += blockDim.x) {
    int k = kp[i];
    int pos = base[k] + atomicAdd(&h[k], 1);
    order[pos] = i;          // bucket order nondeterministic; output row-indexed -> deterministic
    porder[pos] = pp[i];
  }
}

// ---- fused pipelined step kernel ----
// 256 threads = 4 waves; wave w = channel slice wc. TM=32 rows/tile.
// Pipeline: idx prefetched 2 tiles ahead; row gathers issue right after the
// LDS-write barrier (cover = MFMA + epilogue); drain at next top barrier.
template <bool FIRST, bool LAST>
__global__ __launch_bounds__(STEP_THREADS)
void lstm_step_kernel(const _Float16* __restrict__ xf, const _Float16* __restrict__ h_in,
                      const _Float16* __restrict__ c_in,
                      const int* __restrict__ order, const int* __restrict__ porder,
                      const int* __restrict__ counts,
                      const _Float16* __restrict__ WgT, const _Float16* __restrict__ WcT,
                      float* __restrict__ out32, _Float16* __restrict__ h16,
                      _Float16* __restrict__ c16, int bpk) {
  __shared__ __align__(16) _Float16 A[TM][136];   // [h(0:64)|x(64:128)] + pad
  __shared__ __align__(16) _Float16 Cg[TM][72];
  __shared__ int jidx[TM];

  const int kb = blockIdx.x & 7;
  const int bi = blockIdx.x >> 3;
  int cnt = 0, off = 0;
#pragma unroll
  for (int k = 0; k < KNUM; ++k) {
    int c = counts[k];
    if (k < kb) off += c;
    if (k == kb) cnt = c;
  }
  const int ntiles = (cnt + TM - 1) / TM;
  if (bi >= ntiles) return;

  const int lane = threadIdx.x & 63;
  const int wc   = threadIdx.x >> 6;   // 16-channel slice
  const int l15  = lane & 15;
  const int kg   = lane >> 4;

  // B fragments in registers, once per block
  f16x8 bg[4][4];
  f16x8 bc[2];
  {
    const _Float16* wgp = WgT + (size_t)kb * (256 * 128);
#pragma unroll
    for (int g = 0; g < 4; ++g)
#pragma unroll
      for (int ks = (FIRST ? 2 : 0); ks < 4; ++ks)
        bg[g][ks] = *(const f16x8*)(wgp + (size_t)(64 * g + 16 * wc + l15) * 128 + ks * 32 + kg * 8);
    if constexpr (!FIRST) {
      const _Float16* wcp = WcT + (size_t)kb * (64 * 64);
#pragma unroll
      for (int ks = 0; ks < 2; ++ks)
        bc[ks] = *(const f16x8*)(wcp + (size_t)(16 * wc + l15) * 64 + ks * 32 + kg * 8);
    }
  }

  const int gr  = threadIdx.x >> 3;  // gather row 0..31
  const int gq8 = threadIdx.x & 7;   // 8-f16 slice

  int cj, cp; bool cv;   // current tile indices (resident)
  int nj, np; bool nv;   // next tile indices (prefetched)
  f16x8 sx{}, sh{}, sc{};

  auto idx_load = [&](int tt, int& j_, int& p_, bool& v_) {
    int grow = tt * TM + gr;
    v_ = (tt < ntiles) && (grow < cnt);
    j_ = -1; p_ = 0;
    if (v_) {
      if (gq8 == 0) j_ = order[off + grow];
      p_ = porder[off + grow];
    }
  };
  auto rows_load = [&](int p_, bool v_) {
    if (v_) {
      sx = *(const f16x8*)(xf + (size_t)p_ * 64 + gq8 * 8);
      if constexpr (!FIRST) {
        sh = *(const f16x8*)(h_in + (size_t)p_ * 64 + gq8 * 8);
        sc = *(const f16x8*)(c_in + (size_t)p_ * 64 + gq8 * 8);
      }
    } else {
      sx = f16x8{};
      if constexpr (!FIRST) { sh = f16x8{}; sc = f16x8{}; }
    }
  };

  idx_load(bi, cj, cp, cv);
  rows_load(cp, cv);
  idx_load(bi + bpk, nj, np, nv);

  for (int t = bi; t < ntiles; t += bpk) {
    __syncthreads();  // prev tile's LDS readers done; staged loads drained here
    if (gq8 == 0) jidx[gr] = cj;
    *(f16x8*)&A[gr][64 + gq8 * 8] = sx;
    if constexpr (!FIRST) {
      *(f16x8*)&A[gr][gq8 * 8]  = sh;
      *(f16x8*)&Cg[gr][gq8 * 8] = sc;
    }
    __syncthreads();

    // issue next tile's gathers now (idx already resident); prefetch idx t+2
    rows_load(np, nv);
    cj = nj;
    idx_load(t + 2 * bpk, nj, np, nv);

    // MFMA: gates [32x256], c_up [32x64]
    f32x4 aG[2][4];
    f32x4 aC[2];
#pragma unroll
    for (int rf = 0; rf < 2; ++rf) {
#pragma unroll
      for (int g = 0; g < 4; ++g) aG[rf][g] = f32x4{0.f, 0.f, 0.f, 0.f};
      aC[rf] = f32x4{0.f, 0.f, 0.f, 0.f};
    }
#pragma unroll
    for (int ks = (FIRST ? 2 : 0); ks < 4; ++ks) {
#pragma unroll
      for (int rf = 0; rf < 2; ++rf) {
        f16x8 a = *(const f16x8*)&A[16 * rf + l15][ks * 32 + kg * 8];
        aG[rf][0] = __builtin_amdgcn_mfma_f32_16x16x32_f16(a, bg[0][ks], aG[rf][0], 0, 0, 0);
        aG[rf][1] = __builtin_amdgcn_mfma_f32_16x16x32_f16(a, bg[1][ks], aG[rf][1], 0, 0, 0);
        aG[rf][2] = __builtin_amdgcn_mfma_f32_16x16x32_f16(a, bg[2][ks], aG[rf][2], 0, 0, 0);
        aG[rf][3] = __builtin_amdgcn_mfma_f32_16x16x32_f16(a, bg[3][ks], aG[rf][3], 0, 0, 0);
      }
    }
    if constexpr (!FIRST) {
#pragma unroll
      for (int ks = 0; ks < 2; ++ks) {
#pragma unroll
        for (int rf = 0; rf < 2; ++rf) {
          f16x8 a = *(const f16x8*)&Cg[16 * rf + l15][ks * 32 + kg * 8];
          aC[rf] = __builtin_amdgcn_mfma_f32_16x16x32_f16(a, bc[ks], aC[rf], 0, 0, 0);
        }
      }
    }

    // LSTM epilogue + scatter store
#pragma unroll
    for (int rf = 0; rf < 2; ++rf) {
#pragma unroll
      for (int r = 0; r < 4; ++r) {
        int row = 16 * rf + kg * 4 + r;  // C/D: row=(lane>>4)*4+reg, col=lane&15
        int j = jidx[row];
        if (j < 0) continue;
        float ing = fsig(aG[rf][0][r]);
        float fg  = fsig(aG[rf][1][r]);
        float cgt = fsig(aG[rf][2][r]);   // reference uses sigmoid for cell gate
        float og  = fsig(aG[rf][3][r]);
        float cup = FIRST ? 0.0f : aC[rf][r];
        float cxv = fg * cup + ing * cgt;
        float hxv = og * ftanh_(cxv);
        size_t o = (size_t)j * 64 + (16 * wc + l15);
        if constexpr (LAST) {
          out32[o] = hxv;
        } else {
          h16[o] = (_Float16)hxv;
          c16[o] = (_Float16)cxv;
        }
      }
    }
  }
}

static inline int idiv_up(int a, int b) { return (a + b - 1) / b; }

template <bool FIRST, bool LAST>
static void run_step(const _Float16* xf, const _Float16* h_in, const _Float16* c_in,
                     const int* order, const int* porder, int nout, const int* counts,
                     const _Float16* WgT, const _Float16* WcT,
                     float* out32, _Float16* h16, _Float16* c16, hipStream_t stream) {
  int bpk = idiv_up(nout, KNUM * TM);
  if (bpk > 128) bpk = 128;
  if (bpk < 1) bpk = 1;
  lstm_step_kernel<FIRST, LAST><<<dim3(KNUM * bpk), dim3(STEP_THREADS), 0, stream>>>(
      xf, h_in, c_in, order, porder, counts, WgT, WcT, out32, h16, c16, bpk);
}

extern "C" void kernel_launch(void* const* d_in, const int* in_sizes, int n_in,
                              void* d_out, int out_size, void* d_ws, size_t ws_size,
                              hipStream_t stream) {
  const float* x0 = (const float*)d_in[0];
  const float* x1 = (const float*)d_in[1];
  const float* x2 = (const float*)d_in[2];
  const float* Wi = (const float*)d_in[3];
  const float* Wh = (const float*)d_in[4];
  const float* Wc = (const float*)d_in[5];
  const int* parent0 = (const int*)d_in[6];
  const int* kofs0   = (const int*)d_in[7];
  const int* parent1 = (const int*)d_in[8];
  const int* kofs1   = (const int*)d_in[9];
  const int* parent2 = (const int*)d_in[10];
  const int* kofs2   = (const int*)d_in[11];
  const int N1 = in_sizes[6];
  const int N2 = in_sizes[8];
  const int N3 = in_sizes[10];
  const int ne0 = in_sizes[0], ne1 = in_sizes[1], ne2 = in_sizes[2];

  char* w = (char*)d_ws;
  auto carve = [&](size_t bytes) {
    char* p = w;
    w += (bytes + 255) & ~(size_t)255;
    return p;
  };
  _Float16* WgT = (_Float16*)carve((size_t)KNUM * 256 * 128 * 2);
  _Float16* WcT = (_Float16*)carve((size_t)KNUM * 64 * 64 * 2);
  int* counts   = (int*)carve(3 * KNUM * sizeof(int));
  int* cursor   = (int*)carve(3 * KNUM * sizeof(int));
  _Float16* x0f = (_Float16*)carve((size_t)ne0 * 2);
  _Float16* x1f = (_Float16*)carve((size_t)ne1 * 2);
  _Float16* x2f = (_Float16*)carve((size_t)ne2 * 2);
  int* ord0     = (int*)carve((size_t)N1 * sizeof(int));
  int* por0     = (int*)carve((size_t)N1 * sizeof(int));
  int* ord1     = (int*)carve((size_t)N2 * sizeof(int));
  int* por1     = (int*)carve((size_t)N2 * sizeof(int));
  int* ord2     = (int*)carve((size_t)N3 * sizeof(int));
  int* por2     = (int*)carve((size_t)N3 * sizeof(int));
  _Float16* h_a = (_Float16*)carve((size_t)N1 * 64 * 2);
  _Float16* c_a = (_Float16*)carve((size_t)N1 * 64 * 2);
  _Float16* h_b = (_Float16*)carve((size_t)N2 * 64 * 2);
  _Float16* c_b = (_Float16*)carve((size_t)N2 * 64 * 2);
  (void)ws_size; (void)n_in; (void)out_size;

  prep_kernel<<<1024, 256, 0, stream>>>(Wi, Wh, Wc, x0, x1, x2, ne0, ne1, ne2,
                                        WgT, WcT, x0f, x1f, x2f, counts, cursor);
  count_all_kernel<<<512, 256, 0, stream>>>(kofs0, N1, kofs1, N2, kofs2, N3, counts);
  scatter_all_kernel<<<512, 256, 0, stream>>>(kofs0, parent0, N1, ord0, por0,
                                              kofs1, parent1, N2, ord1, por1,
                                              kofs2, parent2, N3, ord2, por2,
                                              counts, cursor);

  run_step<true, false>(x0f, nullptr, nullptr, ord0, por0, N1, counts + 0 * KNUM,
                        WgT, WcT, nullptr, h_a, c_a, stream);
  run_step<false, false>(x1f, h_a, c_a, ord1, por1, N2, counts + 1 * KNUM,
                         WgT, WcT, nullptr, h_b, c_b, stream);
  run_step<false, true>(x2f, h_b, c_b, ord2, por2, N3, counts + 2 * KNUM,
                        WgT, WcT, (float*)d_out, nullptr, nullptr, stream);
}